// Round 16
// baseline (165.996 us; speedup 1.0000x reference)
//
#include <hip/hip_runtime.h>

// ---------------------------------------------------------------------------
// Block_8907762172244 on gfx950 — R15.
// vs R14: k2 main loop = 2-o intervals with 4 rotating cat buffers ->
// 12 barriers instead of 24 (constant B-traffic; 4-deep rotation removes the
// cross-wave WAR race that 3 buffers would have). LDS 53.2KB (3 blk/CU).
// ---------------------------------------------------------------------------

using bf16x8 = __attribute__((ext_vector_type(8))) short;
using f32x4  = __attribute__((ext_vector_type(4))) float;
using f32x2  = __attribute__((ext_vector_type(2))) float;

struct P {
  const float *x, *pos_w, *pos_b;
  const float *ln1g, *ln1b, *ln2g, *ln2b, *ln3g, *ln3b;
  const float *w3a, *b3a, *bn3ag, *bn3ab;
  const float *w3b, *b3b, *bn3bg, *bn3bb;
  const float *w3c, *b3c, *bn3cg, *bn3cb;
  const float *w2, *b2, *bn2g, *bn2b;
  const float *pin_w, *pin_b, *dw_w, *dw_b, *pout_w, *pout_b;
  unsigned short *u;        // [b][w][h][c] bf16
  unsigned short *w2f;      // frag-linear [o][nt][ks][lane][8]
  unsigned short *pinf;     // frag-linear [nt][ks][lane][8]
  unsigned short *poutf;
  float *dwt;               // [9][384]
  float *out;
};

__device__ __forceinline__ unsigned short f2bf(float f) {
  unsigned int v = __float_as_uint(f);
  v += 0x7fffu + ((v >> 16) & 1u);
  return (unsigned short)(v >> 16);
}
__device__ __forceinline__ float bf2f(unsigned short s) {
  return __uint_as_float(((unsigned int)s) << 16);
}
__device__ __forceinline__ unsigned int cvtpk(f32x2 g) {
  unsigned int pk;
  asm("v_cvt_pk_bf16_f32 %0, %1, %2" : "=v"(pk) : "v"(g.x), "v"(g.y));
  return pk;
}

// exact-erf GELU, cephes poly deg-2 in s=u^2 (inputs tiny; err << bf16 quant)
__device__ __forceinline__ f32x2 gelu2p(f32x2 x) {
  f32x2 u = x * 0.70710678118654752f;
  f32x2 s = __builtin_elementwise_min(u * u, f32x2{1.f, 1.f});
  f32x2 pq = __builtin_elementwise_fma(s, f32x2{1.1283585149e-1f, 1.1283585149e-1f},
                                       f32x2{-3.7612625824e-1f, -3.7612625824e-1f});
  pq = __builtin_elementwise_fma(pq, s, f32x2{1.1283791657f, 1.1283791657f});
  f32x2 xh = x * 0.5f;
  return __builtin_elementwise_fma(xh, u * pq, xh);
}

// bijective XCD swizzle: 1024 blocks -> (b, s) with 2 b's per XCD
__device__ __forceinline__ void swz_decode(int bid, int& b, int& s) {
  int xcd = bid & 7, idx = bid >> 3;
  b = xcd * 2 + (idx >> 6);
  s = idx & 63;
}

// ---------------------------------------------------------------------------
__global__ __launch_bounds__(256) void prep(P p) {
  int id = blockIdx.x * 256 + threadIdx.x;
  if (id < 221184) {                       // w2f
    int j = id & 7, l = (id >> 3) & 63, r = id >> 9;
    int ks = r % 3; r /= 3; int nt = r % 6, o = r / 6;
    int d = nt * 16 + (l & 15), y = ks * 32 + (l >> 4) * 8 + j;
    p.w2f[id] = f2bf(p.w2[(d * 24 + o) * 96 + y]);
  } else if (id < 258048) {                // pinf
    int id2 = id - 221184;
    int j = id2 & 7, l = (id2 >> 3) & 63, r = id2 >> 9;
    int ks = r % 3, nt = r / 3;
    int o = nt * 16 + (l & 15), k = ks * 32 + (l >> 4) * 8 + j;
    p.pinf[id2] = f2bf(p.pin_w[o * 96 + k]);
  } else if (id < 276480) {                // poutf
    int id3 = id - 258048;
    int j = id3 & 7, l = (id3 >> 3) & 63, r = id3 >> 9;
    int ks = r % 6, mt = r / 6;
    int d = mt * 16 + (l & 15), cc = ks * 32 + (l >> 4) * 8 + j;
    p.poutf[id3] = f2bf(p.pout_w[d * 192 + cc]);
  } else if (id < 279936) {                // dwt[tap][c]
    int id4 = id - 276480;
    int tap = id4 / 384, c = id4 - tap * 384;
    p.dwt[id4] = p.dw_w[c * 9 + tap];
  }
}

// ---------------------------------------------------------------------------
// cat for one output-channel into buf (no barrier inside)
template <int KSZ>
__device__ __forceinline__ void k2_cat(const float* __restrict__ w3, float b3v,
    float bng, float bnb, float rs, unsigned short* buf,
    const float (&zw)[30], int px, int c0) {
  float sc = bng * rs;
  float wr[KSZ];
  #pragma unroll
  for (int k = 0; k < KSZ; ++k) wr[k] = w3[k] * sc;
  float bias0 = fmaf(b3v, sc, bnb);
  constexpr int OFF = 3 - KSZ / 2;
  unsigned int packed[12];
  #pragma unroll
  for (int e2 = 0; e2 < 12; ++e2) {
    f32x2 f = {bias0, bias0};
    #pragma unroll
    for (int k = 0; k < KSZ; ++k) {
      f32x2 zp = {zw[2 * e2 + OFF + k], zw[2 * e2 + 1 + OFF + k]};
      f = __builtin_elementwise_fma(f32x2{wr[k], wr[k]}, zp, f);
    }
    packed[e2] = cvtpk(gelu2p(f));
  }
  uint4* cw = (uint4*)(buf + px * 104 + c0);
  cw[0] = *(uint4*)&packed[0];
  cw[1] = *(uint4*)&packed[4];
  cw[2] = *(uint4*)&packed[8];
}

// 18 MFMAs of channel o with per-ks 2-deep B staging (R9 form)
__device__ __forceinline__ void k2_mfma(const P& p, int o,
    const unsigned short* cur, int nt0, int ar0, int ar1, f32x4 (&acc)[2][3]) {
  int lane = (threadIdx.x & 63);
  const unsigned short* wf = p.w2f + (size_t)o * 9216 + lane * 8;
  bf16x8 Ba[3], Bb[3];
  #pragma unroll
  for (int n = 0; n < 3; ++n)
    Ba[n] = *(const bf16x8*)(wf + ((nt0 + n) * 3 + 0) * 512);
  #pragma unroll
  for (int n = 0; n < 3; ++n)
    Bb[n] = *(const bf16x8*)(wf + ((nt0 + n) * 3 + 1) * 512);
  {
    bf16x8 a0 = *(const bf16x8*)&cur[ar0];
    bf16x8 a1 = *(const bf16x8*)&cur[ar1];
    #pragma unroll
    for (int n = 0; n < 3; ++n) {
      acc[0][n] = __builtin_amdgcn_mfma_f32_16x16x32_bf16(a0, Ba[n], acc[0][n], 0, 0, 0);
      acc[1][n] = __builtin_amdgcn_mfma_f32_16x16x32_bf16(a1, Ba[n], acc[1][n], 0, 0, 0);
    }
  }
  #pragma unroll
  for (int n = 0; n < 3; ++n)
    Ba[n] = *(const bf16x8*)(wf + ((nt0 + n) * 3 + 2) * 512);
  {
    bf16x8 a0 = *(const bf16x8*)&cur[ar0 + 32];
    bf16x8 a1 = *(const bf16x8*)&cur[ar1 + 32];
    #pragma unroll
    for (int n = 0; n < 3; ++n) {
      acc[0][n] = __builtin_amdgcn_mfma_f32_16x16x32_bf16(a0, Bb[n], acc[0][n], 0, 0, 0);
      acc[1][n] = __builtin_amdgcn_mfma_f32_16x16x32_bf16(a1, Bb[n], acc[1][n], 0, 0, 0);
    }
  }
  {
    bf16x8 a0 = *(const bf16x8*)&cur[ar0 + 64];
    bf16x8 a1 = *(const bf16x8*)&cur[ar1 + 64];
    #pragma unroll
    for (int n = 0; n < 3; ++n) {
      acc[0][n] = __builtin_amdgcn_mfma_f32_16x16x32_bf16(a0, Ba[n], acc[0][n], 0, 0, 0);
      acc[1][n] = __builtin_amdgcn_mfma_f32_16x16x32_bf16(a1, Ba[n], acc[1][n], 0, 0, 0);
    }
  }
}

__global__ __launch_bounds__(256) void k2(P p) {
  __shared__ __align__(16) char smraw[53248];
  unsigned short* cbuf[4] = {
    (unsigned short*)smraw,            (unsigned short*)(smraw + 13312),
    (unsigned short*)(smraw + 26624),  (unsigned short*)(smraw + 39936)};
  float* t1 = (float*)smraw;                     // [96][65] overlay

  int b, h; swz_decode(blockIdx.x, b, h);
  int t = threadIdx.x, lane = t & 63, wv = t >> 6;
  int px = t >> 2, sub = t & 3, c0 = sub * 24;
  const float* xb = p.x + (size_t)b * 96 * 4096;

  // ---- fused k1 head: pos-conv 3x3 + residual -> t1[c][w] ----
  if (t < 192) {
    int c = t >> 1, w0 = (t & 1) * 32;
    const float* xc = xb + (size_t)c * 4096;
    float win[3][34];
    #pragma unroll
    for (int r = 0; r < 3; ++r) {
      int hh = h - 1 + r;
      bool v = (hh >= 0 && hh < 64);
      const float* row = xc + hh * 64;
      #pragma unroll
      for (int i = 0; i < 8; ++i) {
        float4 q = v ? *(const float4*)(row + w0 + i * 4) : make_float4(0,0,0,0);
        win[r][1+i*4] = q.x; win[r][2+i*4] = q.y;
        win[r][3+i*4] = q.z; win[r][4+i*4] = q.w;
      }
      win[r][0]  = (v && w0 > 0)  ? row[w0 - 1]  : 0.f;
      win[r][33] = (v && w0 < 32) ? row[w0 + 32] : 0.f;
    }
    float wt[9];
    #pragma unroll
    for (int i = 0; i < 9; ++i) wt[i] = p.pos_w[c * 9 + i];
    float pb = p.pos_b[c];
    #pragma unroll
    for (int w = 0; w < 32; ++w) {
      float acc = pb;
      #pragma unroll
      for (int r = 0; r < 3; ++r)
        #pragma unroll
        for (int j = 0; j < 3; ++j)
          acc = fmaf(wt[r * 3 + j], win[r][w + j], acc);
      t1[c * 65 + w0 + w] = win[1][w + 1] + acc;
    }
  }
  __syncthreads();

  // ---- quad pass: LN3 residual -> vv (regs), LN1 -> zw ----
  float vv[24];
  float zw[30];
  {
    float s1 = 0.f, s2 = 0.f;
    #pragma unroll
    for (int i = 0; i < 24; ++i) {
      float q = t1[(c0 + i) * 65 + px];
      vv[i] = q; s1 += q; s2 += q * q;
    }
    s1 += __shfl_xor(s1, 1); s1 += __shfl_xor(s1, 2);
    s2 += __shfl_xor(s2, 1); s2 += __shfl_xor(s2, 2);
    float m = s1 * (1.f / 96.f);
    float r = rsqrtf(fmaf(-m, m, s2 * (1.f / 96.f)) + 1e-6f);
    float t1s = 0.f, t2s = 0.f;
    #pragma unroll
    for (int i = 0; i < 24; ++i) {
      int c = c0 + i;
      float y = vv[i] + fmaf((vv[i] - m) * r, p.ln3g[c], p.ln3b[c]);
      vv[i] = y; t1s += y; t2s += y * y;
    }
    t1s += __shfl_xor(t1s, 1); t1s += __shfl_xor(t1s, 2);
    t2s += __shfl_xor(t2s, 1); t2s += __shfl_xor(t2s, 2);
    float m1 = t1s * (1.f / 96.f);
    float r1 = rsqrtf(fmaf(-m1, m1, t2s * (1.f / 96.f)) + 1e-6f);
    #pragma unroll
    for (int i = 0; i < 24; ++i) {
      int c = c0 + i;
      zw[3 + i] = fmaf((vv[i] - m1) * r1, p.ln1g[c], p.ln1b[c]);
    }
  }
  // conv halo from neighbor lanes
  {
    float a0 = __shfl(zw[24], lane - 1), a1 = __shfl(zw[25], lane - 1),
          a2 = __shfl(zw[26], lane - 1);
    float b0 = __shfl(zw[3], lane + 1), b1 = __shfl(zw[4], lane + 1),
          b2 = __shfl(zw[5], lane + 1);
    bool lo = (sub > 0), hi = (sub < 3);
    zw[0] = lo ? a0 : 0.f; zw[1] = lo ? a1 : 0.f; zw[2] = lo ? a2 : 0.f;
    zw[27] = hi ? b0 : 0.f; zw[28] = hi ? b1 : 0.f; zw[29] = hi ? b2 : 0.f;
  }
  __syncthreads();               // t1 reads done -> cat region reusable

  const float rs = rsqrtf(1.f + 1e-5f);
  const int m0 = (wv >> 1) * 32, nt0 = (wv & 1) * 3;
  const int lm = lane & 15, lq = lane >> 4;
  const int ar0 = (m0 + lm) * 104 + lq * 8, ar1 = ar0 + 16 * 104;
  f32x4 acc[2][3];
  #pragma unroll
  for (int m = 0; m < 2; ++m)
    #pragma unroll
    for (int n = 0; n < 3; ++n) acc[m][n] = (f32x4){0.f, 0.f, 0.f, 0.f};

  // prologue: cat(0)->b0, cat(1)->b1
  k2_cat<3>(p.w3a,     p.b3a[0], p.bn3ag[0], p.bn3ab[0], rs, cbuf[0], zw, px, c0);
  k2_cat<3>(p.w3a + 3, p.b3a[1], p.bn3ag[1], p.bn3ab[1], rs, cbuf[1], zw, px, c0);
  __syncthreads();

  // intervals i: MFMA(2i),MFMA(2i+1) from bufs (2i)%4,(2i+1)%4;
  // cat(2i+2),cat(2i+3) into (2i+2)%4,(2i+3)%4; 1 barrier.
  // even i: read b0,b1 write b2,b3 ; odd i: read b2,b3 write b0,b1.
  #pragma unroll
  for (int i = 0; i < 3; ++i) {            // cats ch 2..7 (K3)
    int o = 2 * i;
    const unsigned short* rA = cbuf[(i & 1) ? 2 : 0];
    const unsigned short* rB = cbuf[(i & 1) ? 3 : 1];
    unsigned short* wA = cbuf[(i & 1) ? 0 : 2];
    unsigned short* wB = cbuf[(i & 1) ? 1 : 3];
    k2_mfma(p, o, rA, nt0, ar0, ar1, acc);
    k2_cat<3>(p.w3a + (o + 2) * 3, p.b3a[o + 2], p.bn3ag[o + 2], p.bn3ab[o + 2],
              rs, wA, zw, px, c0);
    k2_mfma(p, o + 1, rB, nt0, ar0, ar1, acc);
    k2_cat<3>(p.w3a + (o + 3) * 3, p.b3a[o + 3], p.bn3ag[o + 3], p.bn3ab[o + 3],
              rs, wB, zw, px, c0);
    __syncthreads();
  }
  #pragma unroll
  for (int i = 3; i < 7; ++i) {            // cats ch 8..15 (K5)
    int o = 2 * i;
    const unsigned short* rA = cbuf[(i & 1) ? 2 : 0];
    const unsigned short* rB = cbuf[(i & 1) ? 3 : 1];
    unsigned short* wA = cbuf[(i & 1) ? 0 : 2];
    unsigned short* wB = cbuf[(i & 1) ? 1 : 3];
    int ca = o + 2 - 8, cb2 = o + 3 - 8;
    k2_mfma(p, o, rA, nt0, ar0, ar1, acc);
    k2_cat<5>(p.w3b + ca * 5, p.b3b[ca], p.bn3bg[ca], p.bn3bb[ca],
              rs, wA, zw, px, c0);
    k2_mfma(p, o + 1, rB, nt0, ar0, ar1, acc);
    k2_cat<5>(p.w3b + cb2 * 5, p.b3b[cb2], p.bn3bg[cb2], p.bn3bb[cb2],
              rs, wB, zw, px, c0);
    __syncthreads();
  }
  #pragma unroll
  for (int i = 7; i < 11; ++i) {           // cats ch 16..23 (K7); i=10 cats 22,23
    int o = 2 * i;
    const unsigned short* rA = cbuf[(i & 1) ? 2 : 0];
    const unsigned short* rB = cbuf[(i & 1) ? 3 : 1];
    unsigned short* wA = cbuf[(i & 1) ? 0 : 2];
    unsigned short* wB = cbuf[(i & 1) ? 1 : 3];
    int ca = o + 2 - 16, cb2 = o + 3 - 16;
    k2_mfma(p, o, rA, nt0, ar0, ar1, acc);
    k2_cat<7>(p.w3c + ca * 7, p.b3c[ca], p.bn3cg[ca], p.bn3cb[ca],
              rs, wA, zw, px, c0);
    k2_mfma(p, o + 1, rB, nt0, ar0, ar1, acc);
    k2_cat<7>(p.w3c + cb2 * 7, p.b3c[cb2], p.bn3cg[cb2], p.bn3cb[cb2],
              rs, wB, zw, px, c0);
    __syncthreads();
  }
  // tail: MFMA(22) b2, MFMA(23) b3 (no cat)
  k2_mfma(p, 22, cbuf[2], nt0, ar0, ar1, acc);
  k2_mfma(p, 23, cbuf[3], nt0, ar0, ar1, acc);
  // b0's last reader (MFMA(20,21)? -> b0,b1) fenced by i=10 barrier; tail
  // reads only b2,b3 -> safe to write g into b0 now.

  // epilogue A: g = GELU(BN2(acc+b2)) -> bf16 into b0
  unsigned short* g0 = cbuf[0];
  #pragma unroll
  for (int mi = 0; mi < 2; ++mi)
    #pragma unroll
    for (int n = 0; n < 3; ++n) {
      int d = (nt0 + n) * 16 + lm;
      float sc2 = p.bn2g[d] * rs, sh2 = p.bn2b[d], bias = p.b2[d];
      int pxb = m0 + mi * 16 + lq * 4;
      unsigned int pk01 = cvtpk(gelu2p(f32x2{fmaf(acc[mi][n][0] + bias, sc2, sh2),
                                             fmaf(acc[mi][n][1] + bias, sc2, sh2)}));
      unsigned int pk23 = cvtpk(gelu2p(f32x2{fmaf(acc[mi][n][2] + bias, sc2, sh2),
                                             fmaf(acc[mi][n][3] + bias, sc2, sh2)}));
      g0[(pxb+0) * 104 + d] = (unsigned short)(pk01 & 0xffffu);
      g0[(pxb+1) * 104 + d] = (unsigned short)(pk01 >> 16);
      g0[(pxb+2) * 104 + d] = (unsigned short)(pk23 & 0xffffu);
      g0[(pxb+3) * 104 + d] = (unsigned short)(pk23 >> 16);
    }
  __syncthreads();

  // epilogue B (owner lane): y2 = g + z + vv(regs); quad-LN2; y3-bf16 -> b1
  unsigned short* y3b = cbuf[1];
  {
    const unsigned int* gsrc = (const unsigned int*)(g0 + px * 104 + c0);
    float s1 = 0.f, s2 = 0.f;
    #pragma unroll
    for (int i2 = 0; i2 < 6; ++i2) {
      unsigned int w0 = gsrc[i2 * 2], w1 = gsrc[i2 * 2 + 1];
      float g0v = __uint_as_float(w0 << 16), g1v = __uint_as_float(w0 & 0xffff0000u);
      float g2v = __uint_as_float(w1 << 16), g3v = __uint_as_float(w1 & 0xffff0000u);
      float y0v = g0v + zw[3 + i2*4 + 0] + vv[i2*4 + 0];
      float y1v = g1v + zw[3 + i2*4 + 1] + vv[i2*4 + 1];
      float y2v = g2v + zw[3 + i2*4 + 2] + vv[i2*4 + 2];
      float y3v = g3v + zw[3 + i2*4 + 3] + vv[i2*4 + 3];
      vv[i2*4+0] = y0v; vv[i2*4+1] = y1v; vv[i2*4+2] = y2v; vv[i2*4+3] = y3v;
      s1 += y0v + y1v + y2v + y3v;
      s2 += y0v*y0v + y1v*y1v + y2v*y2v + y3v*y3v;
    }
    s1 += __shfl_xor(s1, 1); s1 += __shfl_xor(s1, 2);
    s2 += __shfl_xor(s2, 1); s2 += __shfl_xor(s2, 2);
    float m = s1 * (1.f / 96.f);
    float r = rsqrtf(fmaf(-m, m, s2 * (1.f / 96.f)) + 1e-6f);
    unsigned int* dst = (unsigned int*)(y3b + px * 104 + c0);
    #pragma unroll
    for (int i = 0; i < 12; ++i) {
      int c = c0 + 2 * i;
      f32x2 y3p = {fmaf((vv[2*i]   - m) * r, p.ln2g[c],     p.ln2b[c]),
                   fmaf((vv[2*i+1] - m) * r, p.ln2g[c + 1], p.ln2b[c + 1])};
      dst[i] = cvtpk(y3p);
    }
  }
  __syncthreads();

  // fused pin GEMM, operand-swapped: A = pinf (c rows), B = y3 (w cols)
  {
    const int mt = wv;
    bf16x8 B3[3];
    #pragma unroll
    for (int ks = 0; ks < 3; ++ks)
      B3[ks] = *(const bf16x8*)&y3b[(mt * 16 + lm) * 104 + ks * 32 + lq * 8];
    unsigned short* ubh = p.u + (size_t)b * 1572864 + h * 384;
    const int w = mt * 16 + lm;
    unsigned short* urow = ubh + (size_t)w * 24576 + lq * 4;

    bf16x8 An[3];
    const unsigned short* pf0 = p.pinf + lane * 8;
    #pragma unroll
    for (int ks = 0; ks < 3; ++ks)
      An[ks] = *(const bf16x8*)(pf0 + ks * 512);
    for (int nt = 0; nt < 24; ++nt) {
      bf16x8 Af[3] = {An[0], An[1], An[2]};
      if (nt < 23) {
        const unsigned short* pf = p.pinf + ((nt + 1) * 3) * 512 + lane * 8;
        #pragma unroll
        for (int ks = 0; ks < 3; ++ks)
          An[ks] = *(const bf16x8*)(pf + ks * 512);
      }
      f32x4 a4 = (f32x4){0.f, 0.f, 0.f, 0.f};
      #pragma unroll
      for (int ks = 0; ks < 3; ++ks)
        a4 = __builtin_amdgcn_mfma_f32_16x16x32_bf16(Af[ks], B3[ks], a4, 0, 0, 0);
      float4 pbq = *(const float4*)(p.pin_b + nt * 16 + lq * 4);
      unsigned int lo = cvtpk(f32x2{a4[0] + pbq.x, a4[1] + pbq.y});
      unsigned int hi = cvtpk(f32x2{a4[2] + pbq.z, a4[3] + pbq.w});
      *(uint2*)(urow + nt * 16) = make_uint2(lo, hi);
    }
  }
}

// ---------------------------------------------------------------------------
// k4: 192 threads; gate phase all active; MFMA = 3 waves x (2 mt x 4 nt)
__global__ __launch_bounds__(192) void k4(P p) {
  __shared__ __align__(16) char sm4[40960];
  float*          dwl = (float*)sm4;                    // [9][384]
  float*          dbl = (float*)(sm4 + 13824);          // [384]
  unsigned short* gl  = (unsigned short*)(sm4 + 15360); // [64][200]

  int b, w; swz_decode(blockIdx.x, b, w);
  int t = threadIdx.x, lane = t & 63, wv = t >> 6;
  const unsigned short* ub = p.u + (size_t)b * 1572864;

  for (int id = t; id < 3456; id += 192) dwl[id] = p.dwt[id];
  for (int id = t; id < 384; id += 192) dbl[id] = p.dw_b[id];
  __syncthreads();

  {
    int g = t / 24, cb = t - g * 24;
    int c0 = cb * 8, hb = g * 8;
    float4 b1a = *(const float4*)&dbl[c0],       b1b = *(const float4*)&dbl[c0 + 4];
    float4 b2a = *(const float4*)&dbl[192 + c0], b2b = *(const float4*)&dbl[196 + c0];
    const bf16x8 zv = {0,0,0,0,0,0,0,0};
    for (int kk = 0; kk < 4; ++kk) {
      int h0 = hb + kk * 2;
      float v1[2][8], v2[2][8];
      #pragma unroll
      for (int hr = 0; hr < 2; ++hr) {
        v1[hr][0]=b1a.x; v1[hr][1]=b1a.y; v1[hr][2]=b1a.z; v1[hr][3]=b1a.w;
        v1[hr][4]=b1b.x; v1[hr][5]=b1b.y; v1[hr][6]=b1b.z; v1[hr][7]=b1b.w;
        v2[hr][0]=b2a.x; v2[hr][1]=b2a.y; v2[hr][2]=b2a.z; v2[hr][3]=b2a.w;
        v2[hr][4]=b2b.x; v2[hr][5]=b2b.y; v2[hr][6]=b2b.z; v2[hr][7]=b2b.w;
      }
      #pragma unroll
      for (int dw_ = -1; dw_ <= 1; ++dw_) {
        int ww = w + dw_;
        if (ww < 0 || ww > 63) continue;               // block-uniform
        bf16x8 r1[4], r2[4];
        #pragma unroll
        for (int rr = 0; rr < 4; ++rr) {
          int hh = h0 - 1 + rr;
          bool ok = (hh >= 0 && hh <= 63);
          const unsigned short* up = ub + ((size_t)ww * 64 + hh) * 384 + c0;
          r1[rr] = ok ? *(const bf16x8*)up : zv;
          r2[rr] = ok ? *(const bf16x8*)(up + 192) : zv;
        }
        #pragma unroll
        for (int dh = -1; dh <= 1; ++dh) {
          int tap = (dw_ + 1) * 3 + (dh + 1);
          float4 w1a = *(const float4*)&dwl[tap * 384 + c0];
          float4 w1b = *(const float4*)&dwl[tap * 384 + c0 + 4];
          float4 w2a = *(const float4*)&dwl[tap * 384 + 192 + c0];
          float4 w2b = *(const float4*)&dwl[tap * 384 + 196 + c0];
          float wt1[8] = {w1a.x,w1a.y,w1a.z,w1a.w,w1b.x,w1b.y,w1b.z,w1b.w};
          float wt2[8] = {w2a.x,w2a.y,w2a.z,w2a.w,w2b.x,w2b.y,w2b.z,w2b.w};
          #pragma unroll
          for (int hr = 0; hr < 2; ++hr) {
            int rr = hr + dh + 1;
            #pragma unroll
            for (int j = 0; j < 8; ++j) {
              v1[hr][j] = fmaf(wt1[j], bf2f((unsigned short)r1[rr][j]), v1[hr][j]);
              v2[hr][j] = fmaf(wt2[j], bf2f((unsigned short)r2[rr][j]), v2[hr][j]);
            }
          }
        }
      }
      #pragma unroll
      for (int hr = 0; hr < 2; ++hr) {
        unsigned int pk4[4];
        #pragma unroll
        for (int j2 = 0; j2 < 4; ++j2) {
          f32x2 a = {v1[hr][2*j2], v1[hr][2*j2+1]};
          f32x2 bv = {v2[hr][2*j2], v2[hr][2*j2+1]};
          pk4[j2] = cvtpk(gelu2p(a) * bv);
        }
        uint2* dst = (uint2*)(gl + (h0 + hr) * 200 + c0);
        dst[0] = make_uint2(pk4[0], pk4[1]);
        dst[1] = make_uint2(pk4[2], pk4[3]);
      }
    }
  }
  __syncthreads();

  const int lm = lane & 15, lq = lane >> 4;
  const int mtb = wv * 2;                   // wave -> d-tiles {2wv, 2wv+1}
  bf16x8 Af[2][6];
  const unsigned short* pof = p.poutf + lane * 8;
  #pragma unroll
  for (int mi = 0; mi < 2; ++mi)
    #pragma unroll
    for (int ks = 0; ks < 6; ++ks)
      Af[mi][ks] = *(const bf16x8*)(pof + ((mtb + mi) * 6 + ks) * 512);
  f32x4 acc[2][4];
  #pragma unroll
  for (int mi = 0; mi < 2; ++mi)
    #pragma unroll
    for (int n = 0; n < 4; ++n) acc[mi][n] = (f32x4){0.f, 0.f, 0.f, 0.f};
  #pragma unroll
  for (int ks = 0; ks < 6; ++ks) {
    bf16x8 Bg[4];
    #pragma unroll
    for (int n = 0; n < 4; ++n)
      Bg[n] = *(const bf16x8*)&gl[(n * 16 + lm) * 200 + ks * 32 + lq * 8];
    #pragma unroll
    for (int mi = 0; mi < 2; ++mi)
      #pragma unroll
      for (int n = 0; n < 4; ++n)
        acc[mi][n] = __builtin_amdgcn_mfma_f32_16x16x32_bf16(Af[mi][ks], Bg[n], acc[mi][n], 0, 0, 0);
  }
  float* ob = p.out + (size_t)b * 393216 + (size_t)w * 64;
  #pragma unroll
  for (int mi = 0; mi < 2; ++mi)
    #pragma unroll
    for (int r = 0; r < 4; ++r) {
      int d = (mtb + mi) * 16 + lq * 4 + r;
      float pb = p.pout_b[d];
      #pragma unroll
      for (int n = 0; n < 4; ++n) {
        int hcol = n * 16 + lm;
        ob[(size_t)d * 4096 + hcol] = 2.f * (acc[mi][n][r] + pb);
      }
    }
}

// ---------------------------------------------------------------------------
extern "C" void kernel_launch(void* const* d_in, const int* in_sizes, int n_in,
                              void* d_out, int out_size, void* d_ws, size_t ws_size,
                              hipStream_t stream) {
  (void)in_sizes; (void)n_in; (void)out_size; (void)ws_size;
  P p;
  p.x     = (const float*)d_in[0];
  p.pos_w = (const float*)d_in[1];  p.pos_b = (const float*)d_in[2];
  p.ln1g  = (const float*)d_in[3];  p.ln1b  = (const float*)d_in[4];
  p.ln2g  = (const float*)d_in[5];  p.ln2b  = (const float*)d_in[6];
  p.ln3g  = (const float*)d_in[7];  p.ln3b  = (const float*)d_in[8];
  p.w3a   = (const float*)d_in[9];  p.b3a   = (const float*)d_in[10];
  p.bn3ag = (const float*)d_in[11]; p.bn3ab = (const float*)d_in[12];
  p.w3b   = (const float*)d_in[13]; p.b3b   = (const float*)d_in[14];
  p.bn3bg = (const float*)d_in[15]; p.bn3bb = (const float*)d_in[16];
  p.w3c   = (const float*)d_in[17]; p.b3c   = (const float*)d_in[18];
  p.bn3cg = (const float*)d_in[19]; p.bn3cb = (const float*)d_in[20];
  p.w2    = (const float*)d_in[21]; p.b2    = (const float*)d_in[22];
  p.bn2g  = (const float*)d_in[23]; p.bn2b  = (const float*)d_in[24];
  p.pin_w = (const float*)d_in[25]; p.pin_b = (const float*)d_in[26];
  p.dw_w  = (const float*)d_in[27]; p.dw_b  = (const float*)d_in[28];
  p.pout_w= (const float*)d_in[29]; p.pout_b= (const float*)d_in[30];

  char* ws = (char*)d_ws;
  p.u     = (unsigned short*)ws;                          // 50,331,648 B
  p.poutf = (unsigned short*)(ws + 50331648);             // 36,864 B
  p.dwt   = (float*)(ws + 50368512);                      // 13,824 B
  p.w2f   = (unsigned short*)d_out;                       // scratch in d_out
  p.pinf  = (unsigned short*)((char*)d_out + 442368);
  p.out   = (float*)d_out;

  prep<<<dim3(1094), dim3(256), 0, stream>>>(p);
  k2 <<<dim3(1024), dim3(256), 0, stream>>>(p);
  k4 <<<dim3(1024), dim3(192), 0, stream>>>(p);
}

// Round 17
// 150.932 us; speedup vs baseline: 1.0998x; 1.0998x over previous
//
#include <hip/hip_runtime.h>

// ---------------------------------------------------------------------------
// Block_8907762172244 on gfx950 — R16 = R14 checkpoint (best: 151.1 us).
// R15's 12-barrier/4-buffer variant regressed (LDS 53KB -> 3 blk/CU, k2 +12us)
// -> reverted. Final form: fused k1+k2+pin kernel (conv+LN3+LN1 head with
// register-resident y, 24-step dbuf cat/MFMA pipeline, operand-swapped pin
// tail), prep kernel, 192-thread k4. All GELUs = deg-2 erf poly; bf16 MFMA
// everywhere; XCD-aware swizzle.
// ---------------------------------------------------------------------------

using bf16x8 = __attribute__((ext_vector_type(8))) short;
using f32x4  = __attribute__((ext_vector_type(4))) float;
using f32x2  = __attribute__((ext_vector_type(2))) float;

struct P {
  const float *x, *pos_w, *pos_b;
  const float *ln1g, *ln1b, *ln2g, *ln2b, *ln3g, *ln3b;
  const float *w3a, *b3a, *bn3ag, *bn3ab;
  const float *w3b, *b3b, *bn3bg, *bn3bb;
  const float *w3c, *b3c, *bn3cg, *bn3cb;
  const float *w2, *b2, *bn2g, *bn2b;
  const float *pin_w, *pin_b, *dw_w, *dw_b, *pout_w, *pout_b;
  unsigned short *u;        // [b][w][h][c] bf16
  unsigned short *w2f;      // frag-linear [o][nt][ks][lane][8]
  unsigned short *pinf;     // frag-linear [nt][ks][lane][8]
  unsigned short *poutf;
  float *dwt;               // [9][384]
  float *out;
};

__device__ __forceinline__ unsigned short f2bf(float f) {
  unsigned int v = __float_as_uint(f);
  v += 0x7fffu + ((v >> 16) & 1u);
  return (unsigned short)(v >> 16);
}
__device__ __forceinline__ float bf2f(unsigned short s) {
  return __uint_as_float(((unsigned int)s) << 16);
}
__device__ __forceinline__ unsigned int cvtpk(f32x2 g) {
  unsigned int pk;
  asm("v_cvt_pk_bf16_f32 %0, %1, %2" : "=v"(pk) : "v"(g.x), "v"(g.y));
  return pk;
}

// exact-erf GELU, cephes poly deg-2 in s=u^2 (inputs tiny; err << bf16 quant)
__device__ __forceinline__ f32x2 gelu2p(f32x2 x) {
  f32x2 u = x * 0.70710678118654752f;
  f32x2 s = __builtin_elementwise_min(u * u, f32x2{1.f, 1.f});
  f32x2 pq = __builtin_elementwise_fma(s, f32x2{1.1283585149e-1f, 1.1283585149e-1f},
                                       f32x2{-3.7612625824e-1f, -3.7612625824e-1f});
  pq = __builtin_elementwise_fma(pq, s, f32x2{1.1283791657f, 1.1283791657f});
  f32x2 xh = x * 0.5f;
  return __builtin_elementwise_fma(xh, u * pq, xh);
}

// bijective XCD swizzle: 1024 blocks -> (b, s) with 2 b's per XCD
__device__ __forceinline__ void swz_decode(int bid, int& b, int& s) {
  int xcd = bid & 7, idx = bid >> 3;
  b = xcd * 2 + (idx >> 6);
  s = idx & 63;
}

// ---------------------------------------------------------------------------
__global__ __launch_bounds__(256) void prep(P p) {
  int id = blockIdx.x * 256 + threadIdx.x;
  if (id < 221184) {                       // w2f
    int j = id & 7, l = (id >> 3) & 63, r = id >> 9;
    int ks = r % 3; r /= 3; int nt = r % 6, o = r / 6;
    int d = nt * 16 + (l & 15), y = ks * 32 + (l >> 4) * 8 + j;
    p.w2f[id] = f2bf(p.w2[(d * 24 + o) * 96 + y]);
  } else if (id < 258048) {                // pinf
    int id2 = id - 221184;
    int j = id2 & 7, l = (id2 >> 3) & 63, r = id2 >> 9;
    int ks = r % 3, nt = r / 3;
    int o = nt * 16 + (l & 15), k = ks * 32 + (l >> 4) * 8 + j;
    p.pinf[id2] = f2bf(p.pin_w[o * 96 + k]);
  } else if (id < 276480) {                // poutf
    int id3 = id - 258048;
    int j = id3 & 7, l = (id3 >> 3) & 63, r = id3 >> 9;
    int ks = r % 6, mt = r / 6;
    int d = mt * 16 + (l & 15), cc = ks * 32 + (l >> 4) * 8 + j;
    p.poutf[id3] = f2bf(p.pout_w[d * 192 + cc]);
  } else if (id < 279936) {                // dwt[tap][c]
    int id4 = id - 276480;
    int tap = id4 / 384, c = id4 - tap * 384;
    p.dwt[id4] = p.dw_w[c * 9 + tap];
  }
}

// ---------------------------------------------------------------------------
// cat for one output-channel into buf (no barrier inside)
template <int KSZ>
__device__ __forceinline__ void k2_cat(const float* __restrict__ w3, float b3v,
    float bng, float bnb, float rs, unsigned short* buf,
    const float (&zw)[30], int px, int c0) {
  float sc = bng * rs;
  float wr[KSZ];
  #pragma unroll
  for (int k = 0; k < KSZ; ++k) wr[k] = w3[k] * sc;
  float bias0 = fmaf(b3v, sc, bnb);
  constexpr int OFF = 3 - KSZ / 2;
  unsigned int packed[12];
  #pragma unroll
  for (int e2 = 0; e2 < 12; ++e2) {
    f32x2 f = {bias0, bias0};
    #pragma unroll
    for (int k = 0; k < KSZ; ++k) {
      f32x2 zp = {zw[2 * e2 + OFF + k], zw[2 * e2 + 1 + OFF + k]};
      f = __builtin_elementwise_fma(f32x2{wr[k], wr[k]}, zp, f);
    }
    packed[e2] = cvtpk(gelu2p(f));
  }
  uint4* cw = (uint4*)(buf + px * 104 + c0);
  cw[0] = *(uint4*)&packed[0];
  cw[1] = *(uint4*)&packed[4];
  cw[2] = *(uint4*)&packed[8];
}

// one pipeline interval (R9 form): Breg per-ks 2-deep from global, cat(o+1),
// MFMA(o), barrier.
template <int KSZ_NEXT, bool LAST>
__device__ __forceinline__ void k2_step(
    const P& p, int o, const float* __restrict__ w3n, float b3n,
    float bngn, float bnbn, float rs,
    const unsigned short* cur, unsigned short* nxt, const float (&zw)[30],
    int px, int c0, int nt0, int ar0, int ar1, f32x4 (&acc)[2][3]) {
  int lane = (threadIdx.x & 63);
  const unsigned short* wf = p.w2f + (size_t)o * 9216 + lane * 8;
  bf16x8 Ba[3], Bb[3];
  #pragma unroll
  for (int n = 0; n < 3; ++n)
    Ba[n] = *(const bf16x8*)(wf + ((nt0 + n) * 3 + 0) * 512);

  if (!LAST)
    k2_cat<KSZ_NEXT>(w3n, b3n, bngn, bnbn, rs, nxt, zw, px, c0);

  // ks=0: prefetch ks=1, MFMA with Ba
  #pragma unroll
  for (int n = 0; n < 3; ++n)
    Bb[n] = *(const bf16x8*)(wf + ((nt0 + n) * 3 + 1) * 512);
  {
    bf16x8 a0 = *(const bf16x8*)&cur[ar0];
    bf16x8 a1 = *(const bf16x8*)&cur[ar1];
    #pragma unroll
    for (int n = 0; n < 3; ++n) {
      acc[0][n] = __builtin_amdgcn_mfma_f32_16x16x32_bf16(a0, Ba[n], acc[0][n], 0, 0, 0);
      acc[1][n] = __builtin_amdgcn_mfma_f32_16x16x32_bf16(a1, Ba[n], acc[1][n], 0, 0, 0);
    }
  }
  // ks=1: prefetch ks=2 into Ba, MFMA with Bb
  #pragma unroll
  for (int n = 0; n < 3; ++n)
    Ba[n] = *(const bf16x8*)(wf + ((nt0 + n) * 3 + 2) * 512);
  {
    bf16x8 a0 = *(const bf16x8*)&cur[ar0 + 32];
    bf16x8 a1 = *(const bf16x8*)&cur[ar1 + 32];
    #pragma unroll
    for (int n = 0; n < 3; ++n) {
      acc[0][n] = __builtin_amdgcn_mfma_f32_16x16x32_bf16(a0, Bb[n], acc[0][n], 0, 0, 0);
      acc[1][n] = __builtin_amdgcn_mfma_f32_16x16x32_bf16(a1, Bb[n], acc[1][n], 0, 0, 0);
    }
  }
  // ks=2: MFMA with Ba
  {
    bf16x8 a0 = *(const bf16x8*)&cur[ar0 + 64];
    bf16x8 a1 = *(const bf16x8*)&cur[ar1 + 64];
    #pragma unroll
    for (int n = 0; n < 3; ++n) {
      acc[0][n] = __builtin_amdgcn_mfma_f32_16x16x32_bf16(a0, Ba[n], acc[0][n], 0, 0, 0);
      acc[1][n] = __builtin_amdgcn_mfma_f32_16x16x32_bf16(a1, Ba[n], acc[1][n], 0, 0, 0);
    }
  }
  __syncthreads();
}

__global__ __launch_bounds__(256) void k2(P p) {
  __shared__ __align__(16) char smraw[26624];
  unsigned short* cat0 = (unsigned short*)smraw;            // [64][104]
  unsigned short* cat1 = (unsigned short*)(smraw + 13312);  // [64][104]
  float*          t1   = (float*)smraw;                     // [96][65] overlay

  int b, h; swz_decode(blockIdx.x, b, h);
  int t = threadIdx.x, lane = t & 63, wv = t >> 6;
  int px = t >> 2, sub = t & 3, c0 = sub * 24;
  const float* xb = p.x + (size_t)b * 96 * 4096;

  // ---- fused k1 head: pos-conv 3x3 + residual -> t1[c][w] (overlays cat) ----
  if (t < 192) {
    int c = t >> 1, w0 = (t & 1) * 32;
    const float* xc = xb + (size_t)c * 4096;
    float win[3][34];
    #pragma unroll
    for (int r = 0; r < 3; ++r) {
      int hh = h - 1 + r;
      bool v = (hh >= 0 && hh < 64);
      const float* row = xc + hh * 64;
      #pragma unroll
      for (int i = 0; i < 8; ++i) {
        float4 q = v ? *(const float4*)(row + w0 + i * 4) : make_float4(0,0,0,0);
        win[r][1+i*4] = q.x; win[r][2+i*4] = q.y;
        win[r][3+i*4] = q.z; win[r][4+i*4] = q.w;
      }
      win[r][0]  = (v && w0 > 0)  ? row[w0 - 1]  : 0.f;
      win[r][33] = (v && w0 < 32) ? row[w0 + 32] : 0.f;
    }
    float wt[9];
    #pragma unroll
    for (int i = 0; i < 9; ++i) wt[i] = p.pos_w[c * 9 + i];
    float pb = p.pos_b[c];
    #pragma unroll
    for (int w = 0; w < 32; ++w) {
      float acc = pb;
      #pragma unroll
      for (int r = 0; r < 3; ++r)
        #pragma unroll
        for (int j = 0; j < 3; ++j)
          acc = fmaf(wt[r * 3 + j], win[r][w + j], acc);
      t1[c * 65 + w0 + w] = win[1][w + 1] + acc;
    }
  }
  __syncthreads();

  // ---- quad pass: LN3 residual -> vv (REGISTERS, kept to epilogue B),
  //      then LN1 -> zw ----
  float vv[24];                  // y = t + LN3(t): pre-LN1 residual values
  float zw[30];
  {
    float s1 = 0.f, s2 = 0.f;
    #pragma unroll
    for (int i = 0; i < 24; ++i) {
      float q = t1[(c0 + i) * 65 + px];
      vv[i] = q; s1 += q; s2 += q * q;
    }
    s1 += __shfl_xor(s1, 1); s1 += __shfl_xor(s1, 2);
    s2 += __shfl_xor(s2, 1); s2 += __shfl_xor(s2, 2);
    float m = s1 * (1.f / 96.f);
    float r = rsqrtf(fmaf(-m, m, s2 * (1.f / 96.f)) + 1e-6f);
    float t1s = 0.f, t2s = 0.f;
    #pragma unroll
    for (int i = 0; i < 24; ++i) {
      int c = c0 + i;
      float y = vv[i] + fmaf((vv[i] - m) * r, p.ln3g[c], p.ln3b[c]);
      vv[i] = y; t1s += y; t2s += y * y;
    }
    t1s += __shfl_xor(t1s, 1); t1s += __shfl_xor(t1s, 2);
    t2s += __shfl_xor(t2s, 1); t2s += __shfl_xor(t2s, 2);
    float m1 = t1s * (1.f / 96.f);
    float r1 = rsqrtf(fmaf(-m1, m1, t2s * (1.f / 96.f)) + 1e-6f);
    #pragma unroll
    for (int i = 0; i < 24; ++i) {
      int c = c0 + i;
      zw[3 + i] = fmaf((vv[i] - m1) * r1, p.ln1g[c], p.ln1b[c]);
    }
  }
  // conv halo from neighbor lanes
  {
    float a0 = __shfl(zw[24], lane - 1), a1 = __shfl(zw[25], lane - 1),
          a2 = __shfl(zw[26], lane - 1);
    float b0 = __shfl(zw[3], lane + 1), b1 = __shfl(zw[4], lane + 1),
          b2 = __shfl(zw[5], lane + 1);
    bool lo = (sub > 0), hi = (sub < 3);
    zw[0] = lo ? a0 : 0.f; zw[1] = lo ? a1 : 0.f; zw[2] = lo ? a2 : 0.f;
    zw[27] = hi ? b0 : 0.f; zw[28] = hi ? b1 : 0.f; zw[29] = hi ? b2 : 0.f;
  }
  __syncthreads();               // t1 reads done -> cat region reusable

  const float rs = rsqrtf(1.f + 1e-5f);
  const int m0 = (wv >> 1) * 32, nt0 = (wv & 1) * 3;
  const int lm = lane & 15, lq = lane >> 4;
  const int ar0 = (m0 + lm) * 104 + lq * 8, ar1 = ar0 + 16 * 104;
  f32x4 acc[2][3];
  #pragma unroll
  for (int m = 0; m < 2; ++m)
    #pragma unroll
    for (int n = 0; n < 3; ++n) acc[m][n] = (f32x4){0.f, 0.f, 0.f, 0.f};

  // prologue: cat(0)
  k2_cat<3>(p.w3a, p.b3a[0], p.bn3ag[0], p.bn3ab[0], rs, cat0, zw, px, c0);
  __syncthreads();

  for (int o = 0; o < 7; ++o)
    k2_step<3, false>(p, o, p.w3a + (o + 1) * 3, p.b3a[o + 1],
                      p.bn3ag[o + 1], p.bn3ab[o + 1], rs,
                      (o & 1) ? cat1 : cat0, (o & 1) ? cat0 : cat1,
                      zw, px, c0, nt0, ar0, ar1, acc);
  k2_step<5, false>(p, 7, p.w3b, p.b3b[0], p.bn3bg[0], p.bn3bb[0], rs,
                    cat1, cat0, zw, px, c0, nt0, ar0, ar1, acc);
  for (int o = 8; o < 15; ++o)
    k2_step<5, false>(p, o, p.w3b + (o - 7) * 5, p.b3b[o - 7],
                      p.bn3bg[o - 7], p.bn3bb[o - 7], rs,
                      (o & 1) ? cat1 : cat0, (o & 1) ? cat0 : cat1,
                      zw, px, c0, nt0, ar0, ar1, acc);
  k2_step<7, false>(p, 15, p.w3c, p.b3c[0], p.bn3cg[0], p.bn3cb[0], rs,
                    cat1, cat0, zw, px, c0, nt0, ar0, ar1, acc);
  for (int o = 16; o < 23; ++o)
    k2_step<7, false>(p, o, p.w3c + (o - 15) * 7, p.b3c[o - 15],
                      p.bn3cg[o - 15], p.bn3cb[o - 15], rs,
                      (o & 1) ? cat1 : cat0, (o & 1) ? cat0 : cat1,
                      zw, px, c0, nt0, ar0, ar1, acc);
  k2_step<3, true>(p, 23, p.w3a, 0.f, 0.f, 0.f, rs,
                   cat1, cat0, zw, px, c0, nt0, ar0, ar1, acc);

  // epilogue A: g = GELU(BN2(acc+b2)) -> bf16 into cat0
  #pragma unroll
  for (int mi = 0; mi < 2; ++mi)
    #pragma unroll
    for (int n = 0; n < 3; ++n) {
      int d = (nt0 + n) * 16 + lm;
      float sc2 = p.bn2g[d] * rs, sh2 = p.bn2b[d], bias = p.b2[d];
      int pxb = m0 + mi * 16 + lq * 4;
      unsigned int pk01 = cvtpk(gelu2p(f32x2{fmaf(acc[mi][n][0] + bias, sc2, sh2),
                                             fmaf(acc[mi][n][1] + bias, sc2, sh2)}));
      unsigned int pk23 = cvtpk(gelu2p(f32x2{fmaf(acc[mi][n][2] + bias, sc2, sh2),
                                             fmaf(acc[mi][n][3] + bias, sc2, sh2)}));
      cat0[(pxb+0) * 104 + d] = (unsigned short)(pk01 & 0xffffu);
      cat0[(pxb+1) * 104 + d] = (unsigned short)(pk01 >> 16);
      cat0[(pxb+2) * 104 + d] = (unsigned short)(pk23 & 0xffffu);
      cat0[(pxb+3) * 104 + d] = (unsigned short)(pk23 >> 16);
    }
  __syncthreads();

  // epilogue B (owner lane): y2 = g + z + vv(regs); quad-LN2; y3-bf16 -> cat1
  {
    const unsigned int* gsrc = (const unsigned int*)(cat0 + px * 104 + c0);
    float s1 = 0.f, s2 = 0.f;
    #pragma unroll
    for (int i2 = 0; i2 < 6; ++i2) {
      unsigned int w0 = gsrc[i2 * 2], w1 = gsrc[i2 * 2 + 1];
      float g0 = __uint_as_float(w0 << 16), g1 = __uint_as_float(w0 & 0xffff0000u);
      float g2 = __uint_as_float(w1 << 16), g3 = __uint_as_float(w1 & 0xffff0000u);
      float y0v = g0 + zw[3 + i2*4 + 0] + vv[i2*4 + 0];
      float y1v = g1 + zw[3 + i2*4 + 1] + vv[i2*4 + 1];
      float y2v = g2 + zw[3 + i2*4 + 2] + vv[i2*4 + 2];
      float y3v = g3 + zw[3 + i2*4 + 3] + vv[i2*4 + 3];
      vv[i2*4+0] = y0v; vv[i2*4+1] = y1v; vv[i2*4+2] = y2v; vv[i2*4+3] = y3v;
      s1 += y0v + y1v + y2v + y3v;
      s2 += y0v*y0v + y1v*y1v + y2v*y2v + y3v*y3v;
    }
    s1 += __shfl_xor(s1, 1); s1 += __shfl_xor(s1, 2);
    s2 += __shfl_xor(s2, 1); s2 += __shfl_xor(s2, 2);
    float m = s1 * (1.f / 96.f);
    float r = rsqrtf(fmaf(-m, m, s2 * (1.f / 96.f)) + 1e-6f);
    unsigned int* dst = (unsigned int*)(cat1 + px * 104 + c0);
    #pragma unroll
    for (int i = 0; i < 12; ++i) {
      int c = c0 + 2 * i;
      f32x2 y3p = {fmaf((vv[2*i]   - m) * r, p.ln2g[c],     p.ln2b[c]),
                   fmaf((vv[2*i+1] - m) * r, p.ln2g[c + 1], p.ln2b[c + 1])};
      dst[i] = cvtpk(y3p);
    }
  }
  __syncthreads();

  // fused pin GEMM, operand-swapped: A = pinf (c rows), B = y3 (w cols)
  {
    const int mt = wv;
    bf16x8 B3[3];
    #pragma unroll
    for (int ks = 0; ks < 3; ++ks)
      B3[ks] = *(const bf16x8*)&cat1[(mt * 16 + lm) * 104 + ks * 32 + lq * 8];
    unsigned short* ubh = p.u + (size_t)b * 1572864 + h * 384;
    const int w = mt * 16 + lm;
    unsigned short* urow = ubh + (size_t)w * 24576 + lq * 4;

    bf16x8 An[3];
    const unsigned short* pf0 = p.pinf + lane * 8;
    #pragma unroll
    for (int ks = 0; ks < 3; ++ks)
      An[ks] = *(const bf16x8*)(pf0 + ks * 512);
    for (int nt = 0; nt < 24; ++nt) {
      bf16x8 Af[3] = {An[0], An[1], An[2]};
      if (nt < 23) {
        const unsigned short* pf = p.pinf + ((nt + 1) * 3) * 512 + lane * 8;
        #pragma unroll
        for (int ks = 0; ks < 3; ++ks)
          An[ks] = *(const bf16x8*)(pf + ks * 512);
      }
      f32x4 a4 = (f32x4){0.f, 0.f, 0.f, 0.f};
      #pragma unroll
      for (int ks = 0; ks < 3; ++ks)
        a4 = __builtin_amdgcn_mfma_f32_16x16x32_bf16(Af[ks], B3[ks], a4, 0, 0, 0);
      float4 pbq = *(const float4*)(p.pin_b + nt * 16 + lq * 4);
      unsigned int lo = cvtpk(f32x2{a4[0] + pbq.x, a4[1] + pbq.y});
      unsigned int hi = cvtpk(f32x2{a4[2] + pbq.z, a4[3] + pbq.w});
      *(uint2*)(urow + nt * 16) = make_uint2(lo, hi);
    }
  }
}

// ---------------------------------------------------------------------------
// k4: 192 threads; gate phase all active; MFMA = 3 waves x (2 mt x 4 nt)
__global__ __launch_bounds__(192) void k4(P p) {
  __shared__ __align__(16) char sm4[40960];
  float*          dwl = (float*)sm4;                    // [9][384]
  float*          dbl = (float*)(sm4 + 13824);          // [384]
  unsigned short* gl  = (unsigned short*)(sm4 + 15360); // [64][200]

  int b, w; swz_decode(blockIdx.x, b, w);
  int t = threadIdx.x, lane = t & 63, wv = t >> 6;
  const unsigned short* ub = p.u + (size_t)b * 1572864;

  for (int id = t; id < 3456; id += 192) dwl[id] = p.dwt[id];
  for (int id = t; id < 384; id += 192) dbl[id] = p.dw_b[id];
  __syncthreads();

  {
    int g = t / 24, cb = t - g * 24;
    int c0 = cb * 8, hb = g * 8;
    float4 b1a = *(const float4*)&dbl[c0],       b1b = *(const float4*)&dbl[c0 + 4];
    float4 b2a = *(const float4*)&dbl[192 + c0], b2b = *(const float4*)&dbl[196 + c0];
    const bf16x8 zv = {0,0,0,0,0,0,0,0};
    for (int kk = 0; kk < 4; ++kk) {
      int h0 = hb + kk * 2;
      float v1[2][8], v2[2][8];
      #pragma unroll
      for (int hr = 0; hr < 2; ++hr) {
        v1[hr][0]=b1a.x; v1[hr][1]=b1a.y; v1[hr][2]=b1a.z; v1[hr][3]=b1a.w;
        v1[hr][4]=b1b.x; v1[hr][5]=b1b.y; v1[hr][6]=b1b.z; v1[hr][7]=b1b.w;
        v2[hr][0]=b2a.x; v2[hr][1]=b2a.y; v2[hr][2]=b2a.z; v2[hr][3]=b2a.w;
        v2[hr][4]=b2b.x; v2[hr][5]=b2b.y; v2[hr][6]=b2b.z; v2[hr][7]=b2b.w;
      }
      #pragma unroll
      for (int dw_ = -1; dw_ <= 1; ++dw_) {
        int ww = w + dw_;
        if (ww < 0 || ww > 63) continue;               // block-uniform
        bf16x8 r1[4], r2[4];
        #pragma unroll
        for (int rr = 0; rr < 4; ++rr) {
          int hh = h0 - 1 + rr;
          bool ok = (hh >= 0 && hh <= 63);
          const unsigned short* up = ub + ((size_t)ww * 64 + hh) * 384 + c0;
          r1[rr] = ok ? *(const bf16x8*)up : zv;
          r2[rr] = ok ? *(const bf16x8*)(up + 192) : zv;
        }
        #pragma unroll
        for (int dh = -1; dh <= 1; ++dh) {
          int tap = (dw_ + 1) * 3 + (dh + 1);
          float4 w1a = *(const float4*)&dwl[tap * 384 + c0];
          float4 w1b = *(const float4*)&dwl[tap * 384 + c0 + 4];
          float4 w2a = *(const float4*)&dwl[tap * 384 + 192 + c0];
          float4 w2b = *(const float4*)&dwl[tap * 384 + 196 + c0];
          float wt1[8] = {w1a.x,w1a.y,w1a.z,w1a.w,w1b.x,w1b.y,w1b.z,w1b.w};
          float wt2[8] = {w2a.x,w2a.y,w2a.z,w2a.w,w2b.x,w2b.y,w2b.z,w2b.w};
          #pragma unroll
          for (int hr = 0; hr < 2; ++hr) {
            int rr = hr + dh + 1;
            #pragma unroll
            for (int j = 0; j < 8; ++j) {
              v1[hr][j] = fmaf(wt1[j], bf2f((unsigned short)r1[rr][j]), v1[hr][j]);
              v2[hr][j] = fmaf(wt2[j], bf2f((unsigned short)r2[rr][j]), v2[hr][j]);
            }
          }
        }
      }
      #pragma unroll
      for (int hr = 0; hr < 2; ++hr) {
        unsigned int pk4[4];
        #pragma unroll
        for (int j2 = 0; j2 < 4; ++j2) {
          f32x2 a = {v1[hr][2*j2], v1[hr][2*j2+1]};
          f32x2 bv = {v2[hr][2*j2], v2[hr][2*j2+1]};
          pk4[j2] = cvtpk(gelu2p(a) * bv);
        }
        uint2* dst = (uint2*)(gl + (h0 + hr) * 200 + c0);
        dst[0] = make_uint2(pk4[0], pk4[1]);
        dst[1] = make_uint2(pk4[2], pk4[3]);
      }
    }
  }
  __syncthreads();

  const int lm = lane & 15, lq = lane >> 4;
  const int mtb = wv * 2;                   // wave -> d-tiles {2wv, 2wv+1}
  bf16x8 Af[2][6];
  const unsigned short* pof = p.poutf + lane * 8;
  #pragma unroll
  for (int mi = 0; mi < 2; ++mi)
    #pragma unroll
    for (int ks = 0; ks < 6; ++ks)
      Af[mi][ks] = *(const bf16x8*)(pof + ((mtb + mi) * 6 + ks) * 512);
  f32x4 acc[2][4];
  #pragma unroll
  for (int mi = 0; mi < 2; ++mi)
    #pragma unroll
    for (int n = 0; n < 4; ++n) acc[mi][n] = (f32x4){0.f, 0.f, 0.f, 0.f};
  #pragma unroll
  for (int ks = 0; ks < 6; ++ks) {
    bf16x8 Bg[4];
    #pragma unroll
    for (int n = 0; n < 4; ++n)
      Bg[n] = *(const bf16x8*)&gl[(n * 16 + lm) * 200 + ks * 32 + lq * 8];
    #pragma unroll
    for (int mi = 0; mi < 2; ++mi)
      #pragma unroll
      for (int n = 0; n < 4; ++n)
        acc[mi][n] = __builtin_amdgcn_mfma_f32_16x16x32_bf16(Af[mi][ks], Bg[n], acc[mi][n], 0, 0, 0);
  }
  float* ob = p.out + (size_t)b * 393216 + (size_t)w * 64;
  #pragma unroll
  for (int mi = 0; mi < 2; ++mi)
    #pragma unroll
    for (int r = 0; r < 4; ++r) {
      int d = (mtb + mi) * 16 + lq * 4 + r;
      float pb = p.pout_b[d];
      #pragma unroll
      for (int n = 0; n < 4; ++n) {
        int hcol = n * 16 + lm;
        ob[(size_t)d * 4096 + hcol] = 2.f * (acc[mi][n][r] + pb);
      }
    }
}

// ---------------------------------------------------------------------------
extern "C" void kernel_launch(void* const* d_in, const int* in_sizes, int n_in,
                              void* d_out, int out_size, void* d_ws, size_t ws_size,
                              hipStream_t stream) {
  (void)in_sizes; (void)n_in; (void)out_size; (void)ws_size;
  P p;
  p.x     = (const float*)d_in[0];
  p.pos_w = (const float*)d_in[1];  p.pos_b = (const float*)d_in[2];
  p.ln1g  = (const float*)d_in[3];  p.ln1b  = (const float*)d_in[4];
  p.ln2g  = (const float*)d_in[5];  p.ln2b  = (const float*)d_in[6];
  p.ln3g  = (const float*)d_in[7];  p.ln3b  = (const float*)d_in[8];
  p.w3a   = (const float*)d_in[9];  p.b3a   = (const float*)d_in[10];
  p.bn3ag = (const float*)d_in[11]; p.bn3ab = (const float*)d_in[12];
  p.w3b   = (const float*)d_in[13]; p.b3b   = (const float*)d_in[14];
  p.bn3bg = (const float*)d_in[15]; p.bn3bb = (const float*)d_in[16];
  p.w3c   = (const float*)d_in[17]; p.b3c   = (const float*)d_in[18];
  p.bn3cg = (const float*)d_in[19]; p.bn3cb = (const float*)d_in[20];
  p.w2    = (const float*)d_in[21]; p.b2    = (const float*)d_in[22];
  p.bn2g  = (const float*)d_in[23]; p.bn2b  = (const float*)d_in[24];
  p.pin_w = (const float*)d_in[25]; p.pin_b = (const float*)d_in[26];
  p.dw_w  = (const float*)d_in[27]; p.dw_b  = (const float*)d_in[28];
  p.pout_w= (const float*)d_in[29]; p.pout_b= (const float*)d_in[30];

  char* ws = (char*)d_ws;
  p.u     = (unsigned short*)ws;                          // 50,331,648 B
  p.poutf = (unsigned short*)(ws + 50331648);             // 36,864 B
  p.dwt   = (float*)(ws + 50368512);                      // 13,824 B
  p.w2f   = (unsigned short*)d_out;                       // scratch in d_out
  p.pinf  = (unsigned short*)((char*)d_out + 442368);
  p.out   = (float*)d_out;

  prep<<<dim3(1094), dim3(256), 0, stream>>>(p);
  k2 <<<dim3(1024), dim3(256), 0, stream>>>(p);
  k4 <<<dim3(1024), dim3(192), 0, stream>>>(p);
}